// Round 24
// baseline (72.039 us; speedup 1.0000x reference)
//
#include <hip/hip_runtime.h>
#include <math.h>

namespace {

constexpr int D = 256;
constexpr int H = 8;

typedef __attribute__((ext_vector_type(8))) short bf16x8;
typedef __attribute__((ext_vector_type(4))) float f32x4;

__device__ inline unsigned short bf16rn(float x) {
  unsigned u = __builtin_bit_cast(unsigned, x);
  u += 0x7fffu + ((u >> 16) & 1u);
  return (unsigned short)(u >> 16);
}
__device__ inline float bf16tof(unsigned short b) {
  return __builtin_bit_cast(float, (unsigned)b << 16);
}
__device__ inline void hilo8(const float* e, bf16x8& hv, bf16x8& lv) {
  #pragma unroll
  for (int p = 0; p < 8; ++p) {
    unsigned short h = bf16rn(e[p]);
    hv[p] = (short)h;
    lv[p] = (short)bf16rn(e[p] - bf16tof(h));
  }
}

// ---------------- Kernel 1: qW direct (prep+qw merged) -> bf16 qW ----------------
// (byte-identical to R22/R23 — verified)
__global__ __launch_bounds__(256) void qw_direct_kernel(
    const float* __restrict__ q, const float* __restrict__ W,
    unsigned short* __restrict__ qWb) {
  const int tid = threadIdx.x;
  const int w   = blockIdx.x * 4 + (tid >> 6);
  const int l   = tid & 63;
  const int bt  = w >> 6;
  const int hp  = w & 63;
  const int lrow  = l & 15;
  const int lcol8 = (l >> 4) << 3;

  f32x4 acc[2];
  acc[0] = f32x4{0.f, 0.f, 0.f, 0.f};
  acc[1] = f32x4{0.f, 0.f, 0.f, 0.f};

  const float* qbase = q + (size_t)(bt * 16 + lrow) * 256 + lcol8;

  #pragma unroll 2
  for (int ks = 0; ks < 8; ++ks) {
    float ea[8];
    {
      const float4 a0 = *reinterpret_cast<const float4*>(qbase + ks * 32);
      const float4 a1 = *reinterpret_cast<const float4*>(qbase + ks * 32 + 4);
      ea[0] = a0.x; ea[1] = a0.y; ea[2] = a0.z; ea[3] = a0.w;
      ea[4] = a1.x; ea[5] = a1.y; ea[6] = a1.z; ea[7] = a1.w;
    }
    bf16x8 aH, aL;
    hilo8(ea, aH, aL);

    #pragma unroll
    for (int j = 0; j < 2; ++j) {
      const int he = hp * 2 + j;
      const int h  = he >> 4, et = he & 15;
      const float* wp = W + (size_t)h * 65536 +
                        (size_t)(ks * 32 + lcol8) * 256 + et * 16 + lrow;
      float eb[8];
      #pragma unroll
      for (int jj = 0; jj < 8; ++jj) eb[jj] = wp[(size_t)jj * 256];
      bf16x8 bH, bL;
      hilo8(eb, bH, bL);
      acc[j] = __builtin_amdgcn_mfma_f32_16x16x32_bf16(aH, bH, acc[j], 0, 0, 0);
      acc[j] = __builtin_amdgcn_mfma_f32_16x16x32_bf16(aH, bL, acc[j], 0, 0, 0);
      acc[j] = __builtin_amdgcn_mfma_f32_16x16x32_bf16(aL, bH, acc[j], 0, 0, 0);
    }
  }

  const int rbase = (l >> 4) * 4;
  const int col   = l & 15;
  #pragma unroll
  for (int j = 0; j < 2; ++j) {
    const size_t cidx = (size_t)(hp * 2 + j) * 16 + col;
    #pragma unroll
    for (int r = 0; r < 4; ++r) {
      const int bn = bt * 16 + rbase + r;
      qWb[(size_t)bn * 2048 + cidx] = bf16rn(acc[j][r]);
    }
  }
}

// ---------------- Kernel 2: score_stream — m13-shaped k stream ----------------
// Grid (1024, 2) = 2048 blocks, 256 thr, lb(256,8) -> 8 blocks/CU = 32 waves/CU,
// LDS ~13 KB, VGPR <= 64. Wave = one softmax chunk c = 4*kh + wid = k-rows
// 8c..8c+8. Per row: ONE contiguous 1 KB wave-load of the k row + 8 qW ds_reads
// + 32 FMA + shfl-tree reduce. Softmax = R5-verified shfl code; the chunk's
// wsum contribution is its own attn vector; block writes 4-chunk partial wsum.
__global__ __launch_bounds__(256, 8) void score_stream_kernel(
    const unsigned short* __restrict__ qWb, const float* __restrict__ kin,
    const float* __restrict__ bin, float* __restrict__ attn_out,
    float* __restrict__ wsum_ws) {
  __shared__ float qW_lds[8][260];
  __shared__ float s_lds[4][64];
  __shared__ float wpart[4][64];
  const int tid = threadIdx.x;
  const int bn  = blockIdx.x;
  const int kh  = blockIdx.y;
  const int wid = tid >> 6;
  const int ln  = tid & 63;

  // ---- stage qW: bf16 -> f32 LDS (8 x 256, pad 260)
  {
    uint4 qh = *reinterpret_cast<const uint4*>(qWb + (size_t)bn * 2048 + tid * 8);
    const int h = tid >> 5, col = (tid & 31) * 8;
    float4 lo, hi;
    lo.x = bf16tof((unsigned short)(qh.x & 0xffffu));
    lo.y = bf16tof((unsigned short)(qh.x >> 16));
    lo.z = bf16tof((unsigned short)(qh.y & 0xffffu));
    lo.w = bf16tof((unsigned short)(qh.y >> 16));
    hi.x = bf16tof((unsigned short)(qh.z & 0xffffu));
    hi.y = bf16tof((unsigned short)(qh.z >> 16));
    hi.z = bf16tof((unsigned short)(qh.w & 0xffffu));
    hi.w = bf16tof((unsigned short)(qh.w >> 16));
    *reinterpret_cast<float4*>(&qW_lds[h][col])     = lo;
    *reinterpret_cast<float4*>(&qW_lds[h][col + 4]) = hi;
  }
  __syncthreads();

  // ---- scores for chunk c: rows 8c..8c+8, one row at a time (TLP hides latency)
  const int c = 4 * kh + wid;
  const float4* k4 = reinterpret_cast<const float4*>(kin) + (size_t)bn * 4096;
  for (int i = 0; i < 8; ++i) {
    const int row = 8 * c + i;
    float4 kr = k4[(size_t)row * 64 + ln];          // 1 KB contiguous wave-load
    float p[8];
    #pragma unroll
    for (int h2 = 0; h2 < 8; ++h2) {
      float4 qv = *reinterpret_cast<const float4*>(&qW_lds[h2][ln << 2]);
      p[h2] = kr.x * qv.x + kr.y * qv.y + kr.z * qv.z + kr.w * qv.w;
    }
    #pragma unroll
    for (int off = 32; off; off >>= 1) {
      #pragma unroll
      for (int h2 = 0; h2 < 8; ++h2) p[h2] += __shfl_xor(p[h2], off, 64);
    }
    if (ln == 0) {
      #pragma unroll
      for (int h2 = 0; h2 < 8; ++h2) s_lds[wid][i * 8 + h2] = p[h2];
    }
  }

  // ---- softmax over chunk c (elem ln; h = ln&7) — R5-verified shfl pattern
  float x = s_lds[wid][ln] + bin[ln & 7];
  float m = x;
  #pragma unroll
  for (int off = 32; off; off >>= 1) m = fmaxf(m, __shfl_xor(m, off, 64));
  float e = expf(x - m);
  float s = e;
  #pragma unroll
  for (int off = 32; off; off >>= 1) s += __shfl_xor(s, off, 64);
  float a = e / s;
  attn_out[(size_t)bn * 512 + (size_t)c * 64 + ln] = a;
  wpart[wid][ln] = a;          // chunk's contribution to wsum[ln]
  __syncthreads();

  if (tid < 64)
    wsum_ws[((size_t)bn * 2 + kh) * 64 + tid] =
        wpart[0][tid] + wpart[1][tid] + wpart[2][tid] + wpart[3][tid];
}

// ---------------- Kernel 3: PV (R4-measured-fast shape, wsum precomputed) --------
// Grid (1024, 2) = (bn, d-half), 256 thr, lb(256,8).
__global__ __launch_bounds__(256, 8) void pv_kernel(
    const float* __restrict__ vin, const float* __restrict__ wsum_ws,
    float* __restrict__ out) {
  __shared__ float ws[64];
  __shared__ float s_red[8][32][4];
  const int tid = threadIdx.x;
  const int bn  = blockIdx.x;
  const int dh  = blockIdx.y;

  if (tid < 64)
    ws[tid] = wsum_ws[(size_t)bn * 128 + tid] + wsum_ws[(size_t)bn * 128 + 64 + tid];
  __syncthreads();

  const int d4 = tid & 31;
  const int rg = tid >> 5;
  const float4* v4 = reinterpret_cast<const float4*>(vin) +
                     (size_t)bn * 4096 + dh * 32;
  float4 vv[8];
  #pragma unroll
  for (int i = 0; i < 8; ++i) vv[i] = v4[(size_t)(rg + i * 8) * 64 + d4];
  float4 acc = make_float4(0.f, 0.f, 0.f, 0.f);
  #pragma unroll
  for (int i = 0; i < 8; ++i) {
    float w = ws[rg + i * 8];
    acc.x += w * vv[i].x; acc.y += w * vv[i].y;
    acc.z += w * vv[i].z; acc.w += w * vv[i].w;
  }
  *reinterpret_cast<float4*>(&s_red[rg][d4][0]) = acc;
  __syncthreads();

  if (tid < 32) {
    float4 o = make_float4(0.f, 0.f, 0.f, 0.f);
    #pragma unroll
    for (int g = 0; g < 8; ++g) {
      float4 r = *reinterpret_cast<const float4*>(&s_red[g][tid][0]);
      o.x += r.x; o.y += r.y; o.z += r.z; o.w += r.w;
    }
    reinterpret_cast<float4*>(out)[(size_t)bn * 64 + dh * 32 + tid] = o;
  }
}

}  // namespace

extern "C" void kernel_launch(void* const* d_in, const int* in_sizes, int n_in,
                              void* d_out, int out_size, void* d_ws, size_t ws_size,
                              hipStream_t stream) {
  const float* q = (const float*)d_in[0];   // (8,128,1,256)
  const float* k = (const float*)d_in[1];   // (8,128,64,256)
  const float* v = (const float*)d_in[2];   // (8,128,64,256)
  const float* W = (const float*)d_in[3];   // (8,256,256)
  const float* b = (const float*)d_in[4];   // (8,)

  float* out  = (float*)d_out;              // output: 262144 f32
  float* attn = out + 262144;               // attn:   524288 f32
  char*  ws   = (char*)d_ws;
  unsigned short* qWb = (unsigned short*)ws;            // 2 MiB bf16 qW [bn][2048]
  float* wsum_ws = (float*)(ws + ((size_t)2 << 20));    // [bn][2][64] f32 partials

  hipLaunchKernelGGL(qw_direct_kernel,    dim3(1024),    dim3(256), 0, stream, q, W, qWb);
  hipLaunchKernelGGL(score_stream_kernel, dim3(1024, 2), dim3(256), 0, stream,
                     qWb, k, b, attn, wsum_ws);
  hipLaunchKernelGGL(pv_kernel,           dim3(1024, 2), dim3(256), 0, stream,
                     v, wsum_ws, out);
}